// Round 13
// baseline (76.368 us; speedup 1.0000x reference)
//
#include <hip/hip_runtime.h>
#include <hip/hip_bf16.h>

// B=512, T=256, C=384, H=64 single-head causal attention.
// Round 12: GEMM phase -> mfma_f32_32x32x16_bf16.
//   16 waves = 8 row-groups (32 rows) x 2 col-groups (96 cols); acc = 3 x
//   f32x16 = 48 VGPR (M=32/wave finally fits the 128-reg budget). Per-CU
//   LDS B-ingest halves: 1152 ds_read_b128/gen (was 2304).
//   A from global (row = lane&31, k = (lane>>5)*8), 3-deep ring, 24 K-steps.
//   Epilogue: D (col=lane&31, row=(reg&3)+8*(reg>>2)+4*(lane>>5)) routed to
//   qs/kl/vt swizzled LDS tiles. Attn phase = R11 (T12 in-register P,
//   exp2-domain, defer-max).

constexpr int BSZ  = 512;
constexpr int TT   = 256;
constexpr int CDIM = 384;
constexpr int HDIM = 64;
constexpr int NQKV = 192;
// 384^-0.5 (C, not head size) x log2(e): exp(x) == exp2(x*log2e)
constexpr float SCALE2 = 0.07362222313880647f;
constexpr int BTST = 392;   // Bt LDS row stride (784 B)

typedef __attribute__((ext_vector_type(8))) short bf16x8;
typedef __attribute__((ext_vector_type(4))) float f32x4;
typedef __attribute__((ext_vector_type(16))) float f32x16;

__device__ inline unsigned short f2bf(float f) {
    __hip_bfloat16 h = __float2bfloat16(f);
    return *(unsigned short*)&h;
}
__device__ inline bf16x8 pack8(float4 a, float4 b) {
    unsigned short p[8] = { f2bf(a.x), f2bf(a.y), f2bf(a.z), f2bf(a.w),
                            f2bf(b.x), f2bf(b.y), f2bf(b.z), f2bf(b.w) };
    return *(bf16x8*)p;
}
__device__ inline unsigned cvtpk(float lo, float hi) {
    unsigned r;
    asm volatile("v_cvt_pk_bf16_f32 %0, %1, %2" : "=v"(r) : "v"(lo), "v"(hi));
    return r;
}
#define PLSWAP32(a, b) asm volatile("v_permlane32_swap_b32 %0, %1" : "+v"(a), "+v"(b))
#define PLSWAP16(a, b) asm volatile("v_permlane16_swap_b32 %0, %1" : "+v"(a), "+v"(b))

// ---------------- kernel 0: Bt[192][384] bf16 = [Wq|Wk|Wv]^T ----------------
__global__ __launch_bounds__(256) void prep_bt(
    const float* __restrict__ Wq, const float* __restrict__ Wk,
    const float* __restrict__ Wv, unsigned short* __restrict__ bt)
{
    int idx = blockIdx.x * 256 + threadIdx.x;
    if (idx >= NQKV * CDIM) return;
    int n = idx / CDIM, k = idx - n * CDIM;
    const float* W = (n < 64) ? Wq : (n < 128) ? Wk : Wv;
    bt[idx] = f2bf(W[(size_t)k * HDIM + (n & 63)]);
}

// ---------------- fused QKV-projection + flash attention ----------------
__global__ __launch_bounds__(1024) void fused(
    const float* __restrict__ x, const unsigned short* __restrict__ bt,
    float* __restrict__ out)
{
    // GEMM phase: smem = Bt [192][392] (150,528 B)
    // attn phase overlay: qs[256][64] | kl[256][64] | vt[64][256] (all swz)
    __shared__ __align__(16) unsigned short smem[NQKV * BTST];
    unsigned short* btl = smem;
    unsigned short* qs  = smem;
    unsigned short* kl  = smem + 16384;
    unsigned short* vt  = smem + 32768;

    const int b = blockIdx.x, tid = threadIdx.x;
    const int w = tid >> 6, lane = tid & 63;
    const int lr = lane & 15, lk = lane >> 4;
    const int l31 = lane & 31, l5 = lane >> 5;

    // ---- GEMM: wave w = (mg = w>>1, ng = w&1): rows [32mg,32mg+32) x
    //      cols [96ng, 96ng+96), K = 384 in 24 steps of 16 ----
    const int mg = w >> 1, ng = w & 1;
    const float* xr = x + ((size_t)b * TT + 32 * mg + l31) * CDIM + l5 * 8;

    float4 pA[2], pB[2], pC[2];
#define LDCH(P, ks) { \
    P[0] = *(const float4*)&xr[(ks) * 16];     \
    P[1] = *(const float4*)&xr[(ks) * 16 + 4]; }
#define STEP(P, ks, cond) { \
    bf16x8 a = pack8(P[0], P[1]); \
    if (cond) LDCH(P, (ks) + 3); \
    _Pragma("unroll") \
    for (int ci = 0; ci < 3; ++ci) { \
        bf16x8 bb = *(const bf16x8*) \
            &btl[(96 * ng + 32 * ci + l31) * BTST + (ks) * 16 + l5 * 8]; \
        acc[ci] = __builtin_amdgcn_mfma_f32_32x32x16_bf16(a, bb, acc[ci], 0, 0, 0); \
    } }

    // issue chunks 0..2 before Bt staging: memory pipe busy from cycle 0
    LDCH(pA, 0) LDCH(pB, 1) LDCH(pC, 2)

    // ---- stage Bt into LDS: 9216 uint4, 9 per thread, coalesced ----
    #pragma unroll
    for (int p = 0; p < 9; ++p) {
        int i = p * 1024 + tid;
        int row = i / 48, c8 = i - row * 48;
        *(uint4*)&btl[row * BTST + c8 * 8] = ((const uint4*)bt)[i];
    }
    __syncthreads();

    f32x16 acc[3];
    #pragma unroll
    for (int ci = 0; ci < 3; ++ci)
        #pragma unroll
        for (int r = 0; r < 16; ++r) acc[ci][r] = 0.f;

    #pragma unroll
    for (int kk = 0; kk < 8; ++kk) {
        STEP(pA, 3 * kk + 0, kk < 7)
        STEP(pB, 3 * kk + 1, kk < 7)
        STEP(pC, 3 * kk + 2, kk < 7)
    }
#undef LDCH
#undef STEP
    __syncthreads();   // all Bt reads done before overlay writes

    // ---- epilogue: D-frags -> LDS homes.
    //      D: col = 96ng+32ci+l31, row = 32mg + (reg&3) + 8*(reg>>2) + 4*l5.
    #pragma unroll
    for (int ci = 0; ci < 3; ++ci) {
        const int col = 96 * ng + 32 * ci + l31;
        if (col < 64) {            // q: pre-scaled (x log2e), scalar swz writes
            #pragma unroll
            for (int g = 0; g < 4; ++g)
                #pragma unroll
                for (int r = 0; r < 4; ++r) {
                    int row = 32 * mg + r + 8 * g + 4 * l5;
                    qs[row * 64 + (col ^ ((row & 7) << 3))] =
                        f2bf(acc[ci][4 * g + r] * SCALE2);
                }
        } else if (col < 128) {    // k -> kl[t][h] swz
            int c2 = col - 64;
            #pragma unroll
            for (int g = 0; g < 4; ++g)
                #pragma unroll
                for (int r = 0; r < 4; ++r) {
                    int row = 32 * mg + r + 8 * g + 4 * l5;
                    kl[row * 64 + (c2 ^ ((row & 7) << 3))] = f2bf(acc[ci][4 * g + r]);
                }
        } else {                   // v -> vt[h][t] swz, uint2 (4 consecutive t)
            int h = col - 128;
            #pragma unroll
            for (int g = 0; g < 4; ++g) {
                int t0 = 32 * mg + 8 * g + 4 * l5;
                unsigned short pk[4];
                #pragma unroll
                for (int r = 0; r < 4; ++r) pk[r] = f2bf(acc[ci][4 * g + r]);
                *(uint2*)&vt[h * 256 + (t0 ^ ((h & 7) << 3))] = *(uint2*)pk;
            }
        }
    }
    __syncthreads();

    // ---- attention (R11): wave w owns q-rows [16w,16w+16) ----
    const int q0 = 16 * w;
    bf16x8 qa[2];
    #pragma unroll
    for (int kc = 0; kc < 2; ++kc)
        qa[kc] = *(const bf16x8*)
            &qs[(q0 + lr) * 64 + ((kc * 32 + lk * 8) ^ ((lr & 7) << 3))];

    f32x4 oacc[4];
    float mrowL = -INFINITY;   // per-lane running max (log2 domain), q = q0 + lr
    float lpart = 0.f;
    #pragma unroll
    for (int nh = 0; nh < 4; ++nh) oacc[nh] = (f32x4){0.f, 0.f, 0.f, 0.f};

    const int lastt = w >> 2;
    for (int st = 0; st <= lastt; ++st) {
        // S^T = K Q^T: D[s][q]; lane holds q=lr, s = st*64 + ni*16 + lk*4 + r
        f32x4 sa[4];
        #pragma unroll
        for (int ni = 0; ni < 4; ++ni) sa[ni] = (f32x4){0.f, 0.f, 0.f, 0.f};
        #pragma unroll
        for (int ni = 0; ni < 4; ++ni) {
            int row = st * 64 + ni * 16 + lr;
            #pragma unroll
            for (int kc = 0; kc < 2; ++kc) {
                bf16x8 kb = *(const bf16x8*)
                    &kl[row * 64 + ((kc * 32 + lk * 8) ^ ((row & 7) << 3))];
                sa[ni] = __builtin_amdgcn_mfma_f32_16x16x32_bf16(kb, qa[kc], sa[ni], 0, 0, 0);
            }
        }
        // causal mask (diagonal tile only): s > q
        if (st == lastt) {
            #pragma unroll
            for (int ni = 0; ni < 4; ++ni)
                #pragma unroll
                for (int r = 0; r < 4; ++r) {
                    int sg = st * 64 + ni * 16 + lk * 4 + r;
                    if (sg > q0 + lr) sa[ni][r] = -INFINITY;
                }
        }
        // per-lane tile max + 2-round cross-lk reduce
        float pm = sa[0][0];
        #pragma unroll
        for (int ni = 0; ni < 4; ++ni)
            #pragma unroll
            for (int r = 0; r < 4; ++r) pm = fmaxf(pm, sa[ni][r]);
        pm = fmaxf(pm, __shfl_xor(pm, 16));
        pm = fmaxf(pm, __shfl_xor(pm, 32));
        // T13 defer-max: skip rescale when max growth <= 8 (P <= 2^8, bf16-safe)
        if (!__all(pm - mrowL <= 8.0f)) {
            float mn = fmaxf(mrowL, pm);
            float corr = exp2f(mrowL - mn);   // exp2(-inf)=0 first time
            mrowL = mn;
            lpart *= corr;
            #pragma unroll
            for (int r = 0; r < 4; ++r) {
                float ct = __shfl(corr, lk * 4 + r);
                #pragma unroll
                for (int nh = 0; nh < 4; ++nh) oacc[nh][r] *= ct;
            }
        }
        // P = exp2(S - m), per-lane l partial
        #pragma unroll
        for (int ni = 0; ni < 4; ++ni)
            #pragma unroll
            for (int r = 0; r < 4; ++r) {
                float p = exp2f(sa[ni][r] - mrowL);
                sa[ni][r] = p;
                lpart += p;
            }
        // pack P to bf16 words and permute to PV A-frags (T12)
        unsigned Wp[4][2];
        #pragma unroll
        for (int ni = 0; ni < 4; ++ni) {
            Wp[ni][0] = cvtpk(sa[ni][0], sa[ni][1]);
            Wp[ni][1] = cvtpk(sa[ni][2], sa[ni][3]);
        }
        bf16x8 pa[2];
        #pragma unroll
        for (int kc = 0; kc < 2; ++kc) {
            unsigned x0 = Wp[2 * kc][0], y0 = Wp[2 * kc + 1][0];
            PLSWAP32(x0, y0); PLSWAP16(x0, y0);
            unsigned x1 = Wp[2 * kc][1], y1 = Wp[2 * kc + 1][1];
            PLSWAP32(x1, y1); PLSWAP16(x1, y1);
            unsigned wq[4] = {x0, x1, y0, y1};
            pa[kc] = *(bf16x8*)wq;
        }
        // PV: A = pa, B = V^T  -> D[q=lk*4+r][h=nh*16+lr]
        #pragma unroll
        for (int nh = 0; nh < 4; ++nh) {
            int hrow = nh * 16 + lr;
            #pragma unroll
            for (int kc = 0; kc < 2; ++kc) {
                bf16x8 vb = *(const bf16x8*)
                    &vt[hrow * 256 + ((st * 64 + kc * 32 + lk * 8) ^ ((hrow & 7) << 3))];
                oacc[nh] = __builtin_amdgcn_mfma_f32_16x16x32_bf16(pa[kc], vb, oacc[nh], 0, 0, 0);
            }
        }
    }

    // ---- finalize: reduce per-lane l over lk, transpose, normalize ----
    float lsum = lpart;
    lsum += __shfl_xor(lsum, 16);
    lsum += __shfl_xor(lsum, 32);
    float linv[4];
    #pragma unroll
    for (int r = 0; r < 4; ++r)
        linv[r] = 1.0f / __shfl(lsum, lk * 4 + r);
    #pragma unroll
    for (int nh = 0; nh < 4; ++nh)
        #pragma unroll
        for (int r = 0; r < 4; ++r) {
            size_t row = (size_t)b * TT + q0 + lk * 4 + r;
            out[row * HDIM + nh * 16 + lr] = oacc[nh][r] * linv[r];
        }
}

extern "C" void kernel_launch(void* const* d_in, const int* in_sizes, int n_in,
                              void* d_out, int out_size, void* d_ws, size_t ws_size,
                              hipStream_t stream)
{
    const float* x  = (const float*)d_in[0];
    const float* Wq = (const float*)d_in[1];
    const float* Wk = (const float*)d_in[2];
    const float* Wv = (const float*)d_in[3];
    unsigned short* bt = (unsigned short*)d_ws;   // [192][384] bf16 = 147 KB
    float* out = (float*)d_out;

    prep_bt<<<(NQKV * CDIM + 255) / 256, 256, 0, stream>>>(Wq, Wk, Wv, bt);
    fused<<<BSZ, 1024, 0, stream>>>(x, bt, out);
}

// Round 14
// 61.091 us; speedup vs baseline: 1.2501x; 1.2501x over previous
//
#include <hip/hip_runtime.h>
#include <hip/hip_bf16.h>

// B=512, T=256, C=384, H=64 single-head causal attention.
// Round 13: byte-exact revert to Round-10 (empirical best, 61.4 us).
//   GEMM: 16 waves, M=16/wave, acc[12] (48 VGPR), Bt in LDS, 3-deep ring,
//   no barriers in K-loop. Attn: swapped QK^T (mfma(K,Q)), per-lane softmax,
//   P via v_cvt_pk_bf16_f32 + v_permlane32/16_swap (no LDS for P).
// R11's exp2/defer-max and R12's 32x32 MFMA both measured worse -> dropped.

constexpr int BSZ  = 512;
constexpr int TT   = 256;
constexpr int CDIM = 384;
constexpr int HDIM = 64;
constexpr int NQKV = 192;
constexpr float SCALE = 0.051031036307982884f;  // 384^-0.5 (C, not head size)
constexpr int BTST = 392;   // Bt LDS row stride (784 B)

typedef __attribute__((ext_vector_type(8))) short bf16x8;
typedef __attribute__((ext_vector_type(4))) float f32x4;

__device__ inline unsigned short f2bf(float f) {
    __hip_bfloat16 h = __float2bfloat16(f);
    return *(unsigned short*)&h;
}
__device__ inline bf16x8 pack8(float4 a, float4 b) {
    unsigned short p[8] = { f2bf(a.x), f2bf(a.y), f2bf(a.z), f2bf(a.w),
                            f2bf(b.x), f2bf(b.y), f2bf(b.z), f2bf(b.w) };
    return *(bf16x8*)p;
}
__device__ inline unsigned cvtpk(float lo, float hi) {
    unsigned r;
    asm volatile("v_cvt_pk_bf16_f32 %0, %1, %2" : "=v"(r) : "v"(lo), "v"(hi));
    return r;
}
#define PLSWAP32(a, b) asm volatile("v_permlane32_swap_b32 %0, %1" : "+v"(a), "+v"(b))
#define PLSWAP16(a, b) asm volatile("v_permlane16_swap_b32 %0, %1" : "+v"(a), "+v"(b))

// ---------------- kernel 0: Bt[192][384] bf16 = [Wq|Wk|Wv]^T ----------------
__global__ __launch_bounds__(256) void prep_bt(
    const float* __restrict__ Wq, const float* __restrict__ Wk,
    const float* __restrict__ Wv, unsigned short* __restrict__ bt)
{
    int idx = blockIdx.x * 256 + threadIdx.x;
    if (idx >= NQKV * CDIM) return;
    int n = idx / CDIM, k = idx - n * CDIM;
    const float* W = (n < 64) ? Wq : (n < 128) ? Wk : Wv;
    bt[idx] = f2bf(W[(size_t)k * HDIM + (n & 63)]);
}

// ---------------- fused QKV-projection + flash attention ----------------
__global__ __launch_bounds__(1024) void fused(
    const float* __restrict__ x, const unsigned short* __restrict__ bt,
    float* __restrict__ out)
{
    // GEMM phase: smem = Bt [192][392] (150,528 B)
    // attn phase overlay: qs[256][64] (q) | kl[256][64] | vt[64][256]
    __shared__ __align__(16) unsigned short smem[NQKV * BTST];
    unsigned short* btl = smem;
    unsigned short* qs  = smem;
    unsigned short* kl  = smem + 16384;
    unsigned short* vt  = smem + 32768;

    const int b = blockIdx.x, tid = threadIdx.x;
    const int w = tid >> 6, lane = tid & 63;
    const int lr = lane & 15, lk = lane >> 4;

    // ---- GEMM: wave w -> rows [16w,16w+16) x 192, K = 384 ----
    const float* xr0 = x + ((size_t)b * TT + 16 * w + lr) * CDIM + lk * 8;

    float4 pA[2], pB[2], pC[2];
#define LDCH(P, ks) { \
    P[0] = *(const float4*)&xr0[(ks) * 32];     \
    P[1] = *(const float4*)&xr0[(ks) * 32 + 4]; }
#define STEP(P, ks, cond) { \
    bf16x8 a = pack8(P[0], P[1]); \
    if (cond) LDCH(P, (ks) + 3); \
    _Pragma("unroll") \
    for (int ni = 0; ni < 12; ++ni) { \
        bf16x8 bb = *(const bf16x8*)&btl[(ni * 16 + lr) * BTST + (ks) * 32 + lk * 8]; \
        acc[ni] = __builtin_amdgcn_mfma_f32_16x16x32_bf16(a, bb, acc[ni], 0, 0, 0); \
    } }

    // issue chunks 0..2 before Bt staging: memory pipe busy from cycle 0
    LDCH(pA, 0) LDCH(pB, 1) LDCH(pC, 2)

    // ---- stage Bt into LDS: 9216 uint4, 9 per thread, coalesced ----
    #pragma unroll
    for (int p = 0; p < 9; ++p) {
        int i = p * 1024 + tid;
        int row = i / 48, c8 = i - row * 48;
        *(uint4*)&btl[row * BTST + c8 * 8] = ((const uint4*)bt)[i];
    }
    __syncthreads();

    f32x4 acc[12];
    #pragma unroll
    for (int ni = 0; ni < 12; ++ni) acc[ni] = (f32x4){0.f, 0.f, 0.f, 0.f};

    #pragma unroll
    for (int kk = 0; kk < 4; ++kk) {
        STEP(pA, 3 * kk + 0, kk < 3)
        STEP(pB, 3 * kk + 1, kk < 3)
        STEP(pC, 3 * kk + 2, kk < 3)
    }
#undef LDCH
#undef STEP
    __syncthreads();   // all Bt reads done before overlay writes

    // ---- epilogue: D-frags -> LDS homes. D: col=ni*16+lr, rowIn16=lk*4+r ----
    unsigned short* pq = qs + w * 1024;   // wave-private 16x64 (q staging)
    #pragma unroll
    for (int ni = 0; ni < 4; ++ni)        // q: cols 0..63, pre-scaled
        #pragma unroll
        for (int r = 0; r < 4; ++r) {
            int qr = lk * 4 + r;
            int h  = ni * 16 + lr;
            pq[qr * 64 + (h ^ ((qr & 7) << 3))] = f2bf(acc[ni][r] * SCALE);
        }
    #pragma unroll
    for (int ni = 4; ni < 8; ++ni)        // k: cols 64..127 -> kl[t][h] swz
        #pragma unroll
        for (int r = 0; r < 4; ++r) {
            int row = 16 * w + lk * 4 + r;
            int c2  = (ni - 4) * 16 + lr;
            kl[row * 64 + (c2 ^ ((row & 7) << 3))] = f2bf(acc[ni][r]);
        }
    #pragma unroll
    for (int ni = 8; ni < 12; ++ni) {     // v: cols 128..191 -> vt[h][t] swz
        int h  = (ni - 8) * 16 + lr;
        int t0 = 16 * w + lk * 4;
        unsigned short pk[4];
        #pragma unroll
        for (int r = 0; r < 4; ++r) pk[r] = f2bf(acc[ni][r]);
        *(uint2*)&vt[h * 256 + (t0 ^ ((h & 7) << 3))] = *(uint2*)pk;
    }
    __syncthreads();

    // ---- attention: wave w owns q-rows [16w,16w+16) ----
    const int q0 = 16 * w;
    bf16x8 qa[2];
    #pragma unroll
    for (int kc = 0; kc < 2; ++kc)
        qa[kc] = *(const bf16x8*)&pq[lr * 64 + ((kc * 32 + lk * 8) ^ ((lr & 7) << 3))];

    f32x4 oacc[4];
    float mrowL = -INFINITY;   // per-lane stats, q = q0 + lr
    float lpart = 0.f;
    float mrowT[4];            // transposed stats, q = q0 + lk*4 + r
    #pragma unroll
    for (int nh = 0; nh < 4; ++nh) oacc[nh] = (f32x4){0.f, 0.f, 0.f, 0.f};
    #pragma unroll
    for (int r = 0; r < 4; ++r) mrowT[r] = -INFINITY;

    const int lastt = w >> 2;
    for (int st = 0; st <= lastt; ++st) {
        // S^T = K Q^T: D[s][q]; lane holds q=lr, s = st*64 + ni*16 + lk*4 + r
        f32x4 sa[4];
        #pragma unroll
        for (int ni = 0; ni < 4; ++ni) sa[ni] = (f32x4){0.f, 0.f, 0.f, 0.f};
        #pragma unroll
        for (int ni = 0; ni < 4; ++ni) {
            int row = st * 64 + ni * 16 + lr;
            #pragma unroll
            for (int kc = 0; kc < 2; ++kc) {
                bf16x8 kb = *(const bf16x8*)
                    &kl[row * 64 + ((kc * 32 + lk * 8) ^ ((row & 7) << 3))];
                sa[ni] = __builtin_amdgcn_mfma_f32_16x16x32_bf16(kb, qa[kc], sa[ni], 0, 0, 0);
            }
        }
        // causal mask (diagonal tile only): s > q
        if (st == lastt) {
            #pragma unroll
            for (int ni = 0; ni < 4; ++ni) {
                #pragma unroll
                for (int r = 0; r < 4; ++r) {
                    int sg = st * 64 + ni * 16 + lk * 4 + r;
                    if (sg > q0 + lr) sa[ni][r] = -INFINITY;
                }
            }
        }
        // per-lane row max (16 in-lane values) + 2-round cross-lk reduce
        float pm = sa[0][0];
        #pragma unroll
        for (int ni = 0; ni < 4; ++ni)
            #pragma unroll
            for (int r = 0; r < 4; ++r) pm = fmaxf(pm, sa[ni][r]);
        pm = fmaxf(pm, __shfl_xor(pm, 16));
        pm = fmaxf(pm, __shfl_xor(pm, 32));
        float mn = fmaxf(mrowL, pm);
        float corr = __expf(mrowL - mn);   // exp(-inf)=0 first time
        mrowL = mn;
        lpart *= corr;
        // P = exp(S - m), per-lane l partial
        #pragma unroll
        for (int ni = 0; ni < 4; ++ni)
            #pragma unroll
            for (int r = 0; r < 4; ++r) {
                float p = __expf(sa[ni][r] - mn);
                sa[ni][r] = p;
                lpart += p;
            }
        // transposed rescale of oacc (oacc rows are q = q0 + lk*4 + r)
        #pragma unroll
        for (int r = 0; r < 4; ++r) {
            float mt = __shfl(mn, lk * 4 + r);   // lane lk*4+r has q=that index
            float ct = __expf(mrowT[r] - mt);
            mrowT[r] = mt;
            #pragma unroll
            for (int nh = 0; nh < 4; ++nh) oacc[nh][r] *= ct;
        }
        // pack P to bf16 words: Wp[ni][h] = {s=16ni+4lk+2h, +1} at q=lr
        unsigned Wp[4][2];
        #pragma unroll
        for (int ni = 0; ni < 4; ++ni) {
            Wp[ni][0] = cvtpk(sa[ni][0], sa[ni][1]);
            Wp[ni][1] = cvtpk(sa[ni][2], sa[ni][3]);
        }
        // permute to PV A-frags: pa[kc] word g = P[q=lr][s=32kc+8lk+2g..+1]
        bf16x8 pa[2];
        #pragma unroll
        for (int kc = 0; kc < 2; ++kc) {
            unsigned x0 = Wp[2 * kc][0], y0 = Wp[2 * kc + 1][0];
            PLSWAP32(x0, y0); PLSWAP16(x0, y0);   // x0 -> g0, y0 -> g2
            unsigned x1 = Wp[2 * kc][1], y1 = Wp[2 * kc + 1][1];
            PLSWAP32(x1, y1); PLSWAP16(x1, y1);   // x1 -> g1, y1 -> g3
            unsigned wq[4] = {x0, x1, y0, y1};
            pa[kc] = *(bf16x8*)wq;
        }
        // PV: A = pa (P rows=q), B = V^T  -> D[q=lk*4+r][h=nh*16+lr]
        #pragma unroll
        for (int nh = 0; nh < 4; ++nh) {
            int hrow = nh * 16 + lr;
            #pragma unroll
            for (int kc = 0; kc < 2; ++kc) {
                bf16x8 vb = *(const bf16x8*)
                    &vt[hrow * 256 + ((st * 64 + kc * 32 + lk * 8) ^ ((hrow & 7) << 3))];
                oacc[nh] = __builtin_amdgcn_mfma_f32_16x16x32_bf16(pa[kc], vb, oacc[nh], 0, 0, 0);
            }
        }
    }

    // ---- finalize: reduce per-lane l over lk, transpose, normalize ----
    float lsum = lpart;
    lsum += __shfl_xor(lsum, 16);
    lsum += __shfl_xor(lsum, 32);
    float linv[4];
    #pragma unroll
    for (int r = 0; r < 4; ++r)
        linv[r] = 1.0f / __shfl(lsum, lk * 4 + r);
    #pragma unroll
    for (int nh = 0; nh < 4; ++nh)
        #pragma unroll
        for (int r = 0; r < 4; ++r) {
            size_t row = (size_t)b * TT + q0 + lk * 4 + r;
            out[row * HDIM + nh * 16 + lr] = oacc[nh][r] * linv[r];
        }
}

extern "C" void kernel_launch(void* const* d_in, const int* in_sizes, int n_in,
                              void* d_out, int out_size, void* d_ws, size_t ws_size,
                              hipStream_t stream)
{
    const float* x  = (const float*)d_in[0];
    const float* Wq = (const float*)d_in[1];
    const float* Wk = (const float*)d_in[2];
    const float* Wv = (const float*)d_in[3];
    unsigned short* bt = (unsigned short*)d_ws;   // [192][384] bf16 = 147 KB
    float* out = (float*)d_out;

    prep_bt<<<(NQKV * CDIM + 255) / 256, 256, 0, stream>>>(Wq, Wk, Wv, bt);
    fused<<<BSZ, 1024, 0, stream>>>(x, bt, out);
}